// Round 5
// baseline (224.115 us; speedup 1.0000x reference)
//
#include <hip/hip_runtime.h>

#define WAVES 4
#define RPW 4               // rows per wave (wave-private, barrier-free)
#define RPB (RPW * WAVES)   // 16 rows per block
#define NM 14               // Taylor degree (terms 0..14)

using short8 = __attribute__((ext_vector_type(8))) short;
using f32x4  = __attribute__((ext_vector_type(4))) float;

#define LOG2E 1.4426950408889634f

static __device__ __forceinline__ float ex2(float x) { return __builtin_amdgcn_exp2f(x); }
static __device__ __forceinline__ float rcpf_(float x) { return __builtin_amdgcn_rcpf(x); }
static __device__ __forceinline__ float silu_(float x) {
    return x * rcpf_(1.0f + ex2(-x * LOG2E));
}
static __device__ __forceinline__ unsigned short bfhi(float x) {          // truncate
    return (unsigned short)(__float_as_uint(x) >> 16);
}
static __device__ __forceinline__ unsigned short bfrn(float x) {          // round-nearest
    unsigned u = __float_as_uint(x);
    return (unsigned short)((u + 0x7fffu + ((u >> 16) & 1u)) >> 16);
}
static __device__ __forceinline__ float bf2f(unsigned short h) {
    return __uint_as_float(((unsigned)h) << 16);
}

__constant__ float c_invfact[15] = {
    1.f, 1.f, 0.5f, 1.f/6, 1.f/24, 1.f/120, 1.f/720, 1.f/5040, 1.f/40320,
    1.f/362880, 1.f/3628800, 1.f/39916800, 1.f/479001600,
    1.f/6227020800.f, 1.f/87178291200.f};

// ---------------- weight prep in d_ws ---------------------------------------
template <int O, int I>
__device__ __forceinline__ void tr(const float* __restrict__ s, float* __restrict__ d,
                                   int t0, int stride) {
    for (int idx = t0; idx < O * I; idx += stride) {
        int o = idx / I, in = idx - o * I;
        d[in * O + o] = s[idx];
    }
}
template <int N>
__device__ __forceinline__ void cvt(const float* __restrict__ s,
                                    unsigned short* __restrict__ hi,
                                    unsigned short* __restrict__ lo,
                                    int t0, int stride) {
    for (int i = t0; i < N; i += stride) {
        float a = s[i];
        unsigned short h = bfhi(a);
        float r = a - bf2f(h);
        hi[i] = h;
        lo[i] = bfhi(r);
    }
}

__global__ void tweights(const float* __restrict__ s0, const float* __restrict__ s1,
                         const float* __restrict__ s2, const float* __restrict__ s3,
                         const float* __restrict__ s4, const float* __restrict__ s5,
                         const float* __restrict__ s6, const float* __restrict__ s7,
                         const float* __restrict__ s8, float* __restrict__ ws) {
    const int stride = gridDim.x * blockDim.x;
    const int t0 = blockIdx.x * blockDim.x + threadIdx.x;
    tr<128, 12>(s0, ws + 0, t0, stride);                       // WinT fp32 [12][128]
    unsigned short* u4 = (unsigned short*)(ws + 1536);
    cvt<128 * 128>(s1, u4 + 0,     u4 + 16384, t0, stride);    // Aq4 hi/lo [o][in]
    cvt<128 * 128>(s2, u4 + 32768, u4 + 49152, t0, stride);    // Ak4
    cvt<128 * 128>(s3, u4 + 65536, u4 + 81920, t0, stride);    // Av4
    unsigned short* wh = (unsigned short*)(ws + 50688);
    cvt<64 * 128>(s4, wh + 0, wh + 8192, t0, stride);          // Wh hi/lo [64][128]
    unsigned short* u7 = (unsigned short*)(ws + 58880);
    cvt<64 * 64>(s5, u7 + 0,     u7 + 4096,  t0, stride);      // Aq7
    cvt<64 * 64>(s6, u7 + 8192,  u7 + 12288, t0, stride);      // Ak7
    cvt<64 * 64>(s7, u7 + 16384, u7 + 20480, t0, stride);      // Av7
    tr<25, 64>(s8, ws + 71168, t0, stride);                    // WoutT fp32 [64][25]
}

// per-wave scratch: 9312 B (all offsets 16B-aligned)
struct WaveScratch {
    unsigned short hAhi[4][136];    // h / attn4-out bf16 hi, rows 0-3
    unsigned short hAlo[4][136];
    unsigned short h2hi[4][80];     // h2 bf16 hi/lo
    unsigned short h2lo[4][80];
    float sQ[4][132];               // q fp32
    unsigned short sKV[4][132][2];  // (k,v) bf16 packed
    float h3T[64][4];               // attn7 out, transposed
    float sXT[12][4];               // x transposed
    float sY[4][26];                // final y
};

// ---------------- fused per-row network (barrier-free) ----------------------
__global__ __launch_bounds__(256, 4) void fused_net(
    const float* __restrict__ x, const float* __restrict__ ws,
    const float* __restrict__ b_in,
    const float* __restrict__ Bq4, const float* __restrict__ Bk4, const float* __restrict__ Bv4,
    const float* __restrict__ b_h,
    const float* __restrict__ Bq7, const float* __restrict__ Bk7, const float* __restrict__ Bv7,
    const float* __restrict__ b_out,
    float* __restrict__ out) {
    __shared__ __align__(16) WaveScratch S[WAVES];

    const int tid = threadIdx.x;
    const int w = tid >> 6;
    const int l = tid & 63;
    const int row0 = blockIdx.x * RPB + w * RPW;
    const int m16 = l & 15, quad = l >> 4;
    const int g = l & 15, r = l >> 4;      // attention mapping: 16 lanes per row, r in 0..3

    WaveScratch& Sw = S[w];
    const float* WinT  = ws + 0;      // [12][128] fp32
    const float* WoutT = ws + 71168;  // [64][25]  fp32

    // P0: stage x transposed (wave-private slice; within-wave LDS ordering)
    if (l < 12 * RPW) {
        float v = x[row0 * 12 + l];
        int rr = l / 12, in = l - rr * 12;
        Sw.sXT[in][rr] = v;
    }

    // P1: h = silu(x @ Win^T + b_in); lane owns cols 2l,2l+1 of the wave's 4 rows
    {
        float2 bb = *(const float2*)&b_in[2 * l];
        float a0[RPW], a1[RPW];
        #pragma unroll
        for (int rr = 0; rr < RPW; rr++) { a0[rr] = bb.x; a1[rr] = bb.y; }
        #pragma unroll
        for (int in = 0; in < 12; in++) {
            float2 wv = *(const float2*)&WinT[in * 128 + 2 * l];
            float4 xr = *(const float4*)&Sw.sXT[in][0];
            a0[0] = fmaf(xr.x, wv.x, a0[0]); a1[0] = fmaf(xr.x, wv.y, a1[0]);
            a0[1] = fmaf(xr.y, wv.x, a0[1]); a1[1] = fmaf(xr.y, wv.y, a1[1]);
            a0[2] = fmaf(xr.z, wv.x, a0[2]); a1[2] = fmaf(xr.z, wv.y, a1[2]);
            a0[3] = fmaf(xr.w, wv.x, a0[3]); a1[3] = fmaf(xr.w, wv.y, a1[3]);
        }
        #pragma unroll
        for (int rr = 0; rr < RPW; rr++) {
            float h0 = silu_(a0[rr]), h1 = silu_(a1[rr]);
            unsigned short h0h = bfhi(h0), h1h = bfhi(h1);
            float r0 = h0 - bf2f(h0h), r1 = h1 - bf2f(h1h);
            *(unsigned*)&Sw.hAhi[rr][2 * l] = (unsigned)h0h | ((unsigned)h1h << 16);
            *(unsigned*)&Sw.hAlo[rr][2 * l] = (unsigned)bfhi(r0) | ((unsigned)bfhi(r1) << 16);
        }
    }

    // P2: qkv4 via MFMA bf16x3. Wave computes ALL 24 n-tiles for its 4 rows.
    // A rows duplicated (m16&3) -> D rows 0-3 valid (quad 0).
    {
        short8 Ah[4], Al[4];
        #pragma unroll
        for (int kt = 0; kt < 4; kt++) {
            Ah[kt] = *(const short8*)&Sw.hAhi[m16 & 3][kt * 32 + quad * 8];
            Al[kt] = *(const short8*)&Sw.hAlo[m16 & 3][kt * 32 + quad * 8];
        }
        const unsigned short* u4 = (const unsigned short*)(ws + 1536);
        #pragma unroll 4
        for (int t = 0; t < 24; t++) {
            const int mat = t >> 3;            // 0=q,1=k,2=v (wave-uniform)
            const int n = (t & 7) * 16 + m16;
            const float* bp = (mat == 0) ? Bq4 : (mat == 1) ? Bk4 : Bv4;
            float b = bp[n];
            f32x4 acc = {b, b, b, b};
            const unsigned short* Bh = u4 + mat * 32768 + n * 128;
            const unsigned short* Bl = Bh + 16384;
            #pragma unroll
            for (int kt = 0; kt < 4; kt++) {
                short8 bh = *(const short8*)&Bh[kt * 32 + quad * 8];
                short8 bl = *(const short8*)&Bl[kt * 32 + quad * 8];
                acc = __builtin_amdgcn_mfma_f32_16x16x32_bf16(Ah[kt], bh, acc, 0, 0, 0);
                acc = __builtin_amdgcn_mfma_f32_16x16x32_bf16(Ah[kt], bl, acc, 0, 0, 0);
                acc = __builtin_amdgcn_mfma_f32_16x16x32_bf16(Al[kt], bh, acc, 0, 0, 0);
            }
            if (quad == 0) {
                #pragma unroll
                for (int reg = 0; reg < 4; reg++) {
                    float val = silu_(acc[reg]);
                    if (mat == 0)      Sw.sQ[reg][n] = val;
                    else if (mat == 1) Sw.sKV[reg][n][0] = bfrn(val);
                    else               Sw.sKV[reg][n][1] = bfrn(val);
                }
            }
        }
    }

    // P3: attention over 128 via Taylor moments. lane (g,r): j,i in g*8..g*8+7 of row r
    {
        float dmom[NM];       // delta_1..14
        float nmom[NM + 1];   // nu_0..14
        #pragma unroll
        for (int m = 0; m < NM; m++) dmom[m] = 0.f;
        #pragma unroll
        for (int m = 0; m <= NM; m++) nmom[m] = 0.f;
        uint4 u0 = *(const uint4*)&Sw.sKV[r][g * 8][0];
        uint4 u1 = *(const uint4*)&Sw.sKV[r][g * 8 + 4][0];
        unsigned us[8] = {u0.x, u0.y, u0.z, u0.w, u1.x, u1.y, u1.z, u1.w};
        #pragma unroll
        for (int jj = 0; jj < 8; jj++) {
            unsigned u = us[jj];
            float kf = __uint_as_float(u << 16);
            float vf = __uint_as_float(u & 0xffff0000u);
            nmom[0] += vf;
            float p = kf;
            dmom[0] += p; nmom[1] = fmaf(vf, p, nmom[1]);
            #pragma unroll
            for (int m = 1; m < NM; m++) {
                p *= kf;
                dmom[m] += p;
                nmom[m + 1] = fmaf(vf, p, nmom[m + 1]);
            }
        }
        #pragma unroll
        for (int m = 0; m < NM; m++) {
            float v = dmom[m];
            v += __shfl_xor(v, 1); v += __shfl_xor(v, 2);
            v += __shfl_xor(v, 4); v += __shfl_xor(v, 8);
            dmom[m] = v;
        }
        #pragma unroll
        for (int m = 0; m <= NM; m++) {
            float v = nmom[m];
            v += __shfl_xor(v, 1); v += __shfl_xor(v, 2);
            v += __shfl_xor(v, 4); v += __shfl_xor(v, 8);
            nmom[m] = v;
        }
        float cd[NM + 1], cn[NM + 1];
        cd[0] = 128.f; cn[0] = nmom[0];
        #pragma unroll
        for (int m = 1; m <= NM; m++) {
            cd[m] = dmom[m - 1] * c_invfact[m];
            cn[m] = nmom[m] * c_invfact[m];
        }
        float4 qa = *(const float4*)&Sw.sQ[r][g * 8];
        float4 qb = *(const float4*)&Sw.sQ[r][g * 8 + 4];
        float qs[8] = {qa.x, qa.y, qa.z, qa.w, qb.x, qb.y, qb.z, qb.w};
        unsigned hiw[4], low[4];
        #pragma unroll
        for (int i = 0; i < 8; i++) {
            float t = qs[i];
            float d = cd[NM], nn = cn[NM];
            #pragma unroll
            for (int m = NM - 1; m >= 0; m--) {
                d = fmaf(d, t, cd[m]);
                nn = fmaf(nn, t, cn[m]);
            }
            float o = silu_(nn * rcpf_(d));
            unsigned short oh = bfhi(o);
            unsigned short olo = bfhi(o - bf2f(oh));
            if (i & 1) { hiw[i >> 1] |= ((unsigned)oh) << 16; low[i >> 1] |= ((unsigned)olo) << 16; }
            else       { hiw[i >> 1] = oh; low[i >> 1] = olo; }
        }
        *(uint4*)&Sw.hAhi[r][g * 8] = make_uint4(hiw[0], hiw[1], hiw[2], hiw[3]);
        *(uint4*)&Sw.hAlo[r][g * 8] = make_uint4(low[0], low[1], low[2], low[3]);
    }

    // P4: h2 = silu(attn4 @ Wh^T + b_h). K=128, N=64: 4 n-tiles, all by this wave.
    {
        short8 Ah[4], Al[4];
        #pragma unroll
        for (int kt = 0; kt < 4; kt++) {
            Ah[kt] = *(const short8*)&Sw.hAhi[m16 & 3][kt * 32 + quad * 8];
            Al[kt] = *(const short8*)&Sw.hAlo[m16 & 3][kt * 32 + quad * 8];
        }
        const unsigned short* whh = (const unsigned short*)(ws + 50688);
        const unsigned short* whl = whh + 8192;
        #pragma unroll
        for (int t = 0; t < 4; t++) {
            const int n = t * 16 + m16;
            float b = b_h[n];
            f32x4 acc = {b, b, b, b};
            #pragma unroll
            for (int kt = 0; kt < 4; kt++) {
                short8 bh = *(const short8*)&whh[n * 128 + kt * 32 + quad * 8];
                short8 bl = *(const short8*)&whl[n * 128 + kt * 32 + quad * 8];
                acc = __builtin_amdgcn_mfma_f32_16x16x32_bf16(Ah[kt], bh, acc, 0, 0, 0);
                acc = __builtin_amdgcn_mfma_f32_16x16x32_bf16(Ah[kt], bl, acc, 0, 0, 0);
                acc = __builtin_amdgcn_mfma_f32_16x16x32_bf16(Al[kt], bh, acc, 0, 0, 0);
            }
            if (quad == 0) {
                #pragma unroll
                for (int reg = 0; reg < 4; reg++) {
                    float hv = silu_(acc[reg]);
                    unsigned short hh = bfhi(hv);
                    Sw.h2hi[reg][n] = hh;
                    Sw.h2lo[reg][n] = bfhi(hv - bf2f(hh));
                }
            }
        }
    }

    // P5: qkv7 via MFMA bf16x3. K=64, N=192: 12 n-tiles, all by this wave.
    {
        short8 Ah[2], Al[2];
        #pragma unroll
        for (int kt = 0; kt < 2; kt++) {
            Ah[kt] = *(const short8*)&Sw.h2hi[m16 & 3][kt * 32 + quad * 8];
            Al[kt] = *(const short8*)&Sw.h2lo[m16 & 3][kt * 32 + quad * 8];
        }
        const unsigned short* u7 = (const unsigned short*)(ws + 58880);
        #pragma unroll 4
        for (int t = 0; t < 12; t++) {
            const int mat = t >> 2;            // 0=q,1=k,2=v
            const int n = (t & 3) * 16 + m16;
            const float* bp = (mat == 0) ? Bq7 : (mat == 1) ? Bk7 : Bv7;
            float b = bp[n];
            f32x4 acc = {b, b, b, b};
            const unsigned short* Bh = u7 + mat * 8192 + n * 64;
            const unsigned short* Bl = Bh + 4096;
            #pragma unroll
            for (int kt = 0; kt < 2; kt++) {
                short8 bh = *(const short8*)&Bh[kt * 32 + quad * 8];
                short8 bl = *(const short8*)&Bl[kt * 32 + quad * 8];
                acc = __builtin_amdgcn_mfma_f32_16x16x32_bf16(Ah[kt], bh, acc, 0, 0, 0);
                acc = __builtin_amdgcn_mfma_f32_16x16x32_bf16(Ah[kt], bl, acc, 0, 0, 0);
                acc = __builtin_amdgcn_mfma_f32_16x16x32_bf16(Al[kt], bh, acc, 0, 0, 0);
            }
            if (quad == 0) {
                #pragma unroll
                for (int reg = 0; reg < 4; reg++) {
                    float val = silu_(acc[reg]);
                    if (mat == 0)      Sw.sQ[reg][n] = val;
                    else if (mat == 1) Sw.sKV[reg][n][0] = bfrn(val);
                    else               Sw.sKV[reg][n][1] = bfrn(val);
                }
            }
        }
    }

    // P6: attention over 64 via Taylor moments; lane (g,r): j,i in g*4..g*4+3
    {
        float dmom[NM];
        float nmom[NM + 1];
        #pragma unroll
        for (int m = 0; m < NM; m++) dmom[m] = 0.f;
        #pragma unroll
        for (int m = 0; m <= NM; m++) nmom[m] = 0.f;
        uint4 u0 = *(const uint4*)&Sw.sKV[r][g * 4][0];
        unsigned us[4] = {u0.x, u0.y, u0.z, u0.w};
        #pragma unroll
        for (int jj = 0; jj < 4; jj++) {
            unsigned u = us[jj];
            float kf = __uint_as_float(u << 16);
            float vf = __uint_as_float(u & 0xffff0000u);
            nmom[0] += vf;
            float p = kf;
            dmom[0] += p; nmom[1] = fmaf(vf, p, nmom[1]);
            #pragma unroll
            for (int m = 1; m < NM; m++) {
                p *= kf;
                dmom[m] += p;
                nmom[m + 1] = fmaf(vf, p, nmom[m + 1]);
            }
        }
        #pragma unroll
        for (int m = 0; m < NM; m++) {
            float v = dmom[m];
            v += __shfl_xor(v, 1); v += __shfl_xor(v, 2);
            v += __shfl_xor(v, 4); v += __shfl_xor(v, 8);
            dmom[m] = v;
        }
        #pragma unroll
        for (int m = 0; m <= NM; m++) {
            float v = nmom[m];
            v += __shfl_xor(v, 1); v += __shfl_xor(v, 2);
            v += __shfl_xor(v, 4); v += __shfl_xor(v, 8);
            nmom[m] = v;
        }
        float cd[NM + 1], cn[NM + 1];
        cd[0] = 64.f; cn[0] = nmom[0];
        #pragma unroll
        for (int m = 1; m <= NM; m++) {
            cd[m] = dmom[m - 1] * c_invfact[m];
            cn[m] = nmom[m] * c_invfact[m];
        }
        float4 qa = *(const float4*)&Sw.sQ[r][g * 4];
        float qs[4] = {qa.x, qa.y, qa.z, qa.w};
        #pragma unroll
        for (int i = 0; i < 4; i++) {
            float t = qs[i];
            float d = cd[NM], nn = cn[NM];
            #pragma unroll
            for (int m = NM - 1; m >= 0; m--) {
                d = fmaf(d, t, cd[m]);
                nn = fmaf(nn, t, cn[m]);
            }
            Sw.h3T[g * 4 + i][r] = silu_(nn * rcpf_(d));
        }
    }

    // P7: y = silu(attn7 @ Wout^T + b_out), 64 -> 25, split across lane halves
    {
        const int o = l & 31;
        const int half = l >> 5;
        const int oc = (o < 25) ? o : 0;
        float y[RPW];
        float bb = (half == 0) ? b_out[oc] : 0.f;
        #pragma unroll
        for (int rr = 0; rr < RPW; rr++) y[rr] = bb;
        const int in0 = half * 32;
        #pragma unroll 4
        for (int i = 0; i < 32; i++) {
            int in = in0 + i;
            float wv = WoutT[in * 25 + oc];
            float4 xr = *(const float4*)&Sw.h3T[in][0];
            y[0] = fmaf(xr.x, wv, y[0]);
            y[1] = fmaf(xr.y, wv, y[1]);
            y[2] = fmaf(xr.z, wv, y[2]);
            y[3] = fmaf(xr.w, wv, y[3]);
        }
        #pragma unroll
        for (int rr = 0; rr < RPW; rr++) {
            float full = y[rr] + __shfl_xor(y[rr], 32, 64);
            if (l < 25) Sw.sY[rr][l] = silu_(full);
        }
    }

    // P8: quadratic epilogue; lanes l < RPW, one row each
    if (l < RPW) {
        const int rr = l;
        float y[25];
        #pragma unroll
        for (int c = 0; c < 25; c++) y[c] = Sw.sY[rr][c];
        float M11 = 0.f, M12 = 0.f, M21 = 0.f, M22 = 0.f, Mpp = 0.f;
        #pragma unroll
        for (int c = 0; c < 5; c++) {
            M11 = fmaf(y[c], y[c], M11);
            M12 = fmaf(y[5 + c], y[5 + c], M12);
            M21 = fmaf(y[10 + c], y[10 + c], M21);
            M22 = fmaf(y[15 + c], y[15 + c], M22);
            Mpp = fmaf(y[20 + c], y[20 + c], Mpp);
        }
        float quad = M11 * (y[0] * y[0] + y[1] * y[1])
                   + (M12 + M21) * (y[0] * y[2] + y[1] * y[3])
                   + M22 * (y[2] * y[2] + y[3] * y[3]);
        out[row0 + rr] = quad + Mpp;
    }
}

extern "C" void kernel_launch(void* const* d_in, const int* in_sizes, int n_in,
                              void* d_out, int out_size, void* d_ws, size_t ws_size,
                              hipStream_t stream) {
    const float* x    = (const float*)d_in[0];
    const float* W_in = (const float*)d_in[2];
    const float* b_in = (const float*)d_in[3];
    const float* Aq4  = (const float*)d_in[4];
    const float* Bq4  = (const float*)d_in[5];
    const float* Ak4  = (const float*)d_in[6];
    const float* Bk4  = (const float*)d_in[7];
    const float* Av4  = (const float*)d_in[8];
    const float* Bv4  = (const float*)d_in[9];
    const float* W_h  = (const float*)d_in[10];
    const float* b_h  = (const float*)d_in[11];
    const float* Aq7  = (const float*)d_in[12];
    const float* Bq7  = (const float*)d_in[13];
    const float* Ak7  = (const float*)d_in[14];
    const float* Bk7  = (const float*)d_in[15];
    const float* Av7  = (const float*)d_in[16];
    const float* Bv7  = (const float*)d_in[17];
    const float* Wout = (const float*)d_in[18];
    const float* bout = (const float*)d_in[19];
    float* ws = (float*)d_ws;

    tweights<<<128, 256, 0, stream>>>(W_in, Aq4, Ak4, Av4, W_h, Aq7, Ak7, Av7, Wout, ws);

    const int B = in_sizes[0] / 12;        // 16384
    const int grid = B / RPB;              // 1024
    fused_net<<<grid, 256, 0, stream>>>(x, ws, b_in, Bq4, Bk4, Bv4,
                                        b_h, Bq7, Bk7, Bv7, bout, (float*)d_out);
}

// Round 6
// 139.424 us; speedup vs baseline: 1.6074x; 1.6074x over previous
//
#include <hip/hip_runtime.h>

#define RPW 4            // rows per wave
#define WAVES 4
#define RPB (RPW * WAVES)   // 16 rows per block
#define NM 14               // Taylor degree (terms 0..14)

using short8 = __attribute__((ext_vector_type(8))) short;
using f32x4  = __attribute__((ext_vector_type(4))) float;

#define LOG2E 1.4426950408889634f

static __device__ __forceinline__ float ex2(float x) { return __builtin_amdgcn_exp2f(x); }
static __device__ __forceinline__ float rcpf_(float x) { return __builtin_amdgcn_rcpf(x); }
static __device__ __forceinline__ float silu_(float x) {
    return x * rcpf_(1.0f + ex2(-x * LOG2E));
}
static __device__ __forceinline__ unsigned short bfhi(float x) {          // truncate
    return (unsigned short)(__float_as_uint(x) >> 16);
}
static __device__ __forceinline__ unsigned short bfrn(float x) {          // round-nearest
    unsigned u = __float_as_uint(x);
    return (unsigned short)((u + 0x7fffu + ((u >> 16) & 1u)) >> 16);
}
static __device__ __forceinline__ float bf2f(unsigned short h) {
    return __uint_as_float(((unsigned)h) << 16);
}

__constant__ float c_invfact[15] = {
    1.f, 1.f, 0.5f, 1.f/6, 1.f/24, 1.f/120, 1.f/720, 1.f/5040, 1.f/40320,
    1.f/362880, 1.f/3628800, 1.f/39916800, 1.f/479001600,
    1.f/6227020800.f, 1.f/87178291200.f};

// ---------------- weight prep in d_ws ---------------------------------------
template <int O, int I>
__device__ __forceinline__ void tr(const float* __restrict__ s, float* __restrict__ d,
                                   int t0, int stride) {
    for (int idx = t0; idx < O * I; idx += stride) {
        int o = idx / I, in = idx - o * I;
        d[in * O + o] = s[idx];
    }
}
template <int N>
__device__ __forceinline__ void cvt(const float* __restrict__ s,
                                    unsigned short* __restrict__ hi,
                                    unsigned short* __restrict__ lo,
                                    int t0, int stride) {
    for (int i = t0; i < N; i += stride) {
        float a = s[i];
        unsigned short h = bfhi(a);
        float r = a - bf2f(h);
        hi[i] = h;
        lo[i] = bfhi(r);
    }
}

__global__ void tweights(const float* __restrict__ s0, const float* __restrict__ s1,
                         const float* __restrict__ s2, const float* __restrict__ s3,
                         const float* __restrict__ s4, const float* __restrict__ s5,
                         const float* __restrict__ s6, const float* __restrict__ s7,
                         const float* __restrict__ s8, float* __restrict__ ws) {
    const int stride = gridDim.x * blockDim.x;
    const int t0 = blockIdx.x * blockDim.x + threadIdx.x;
    tr<128, 12>(s0, ws + 0, t0, stride);                       // WinT fp32 [12][128]
    unsigned short* u4 = (unsigned short*)(ws + 1536);
    cvt<128 * 128>(s1, u4 + 0,     u4 + 16384, t0, stride);    // Aq4 hi/lo [o][in]
    cvt<128 * 128>(s2, u4 + 32768, u4 + 49152, t0, stride);    // Ak4
    cvt<128 * 128>(s3, u4 + 65536, u4 + 81920, t0, stride);    // Av4
    unsigned short* wh = (unsigned short*)(ws + 50688);
    cvt<64 * 128>(s4, wh + 0, wh + 8192, t0, stride);          // Wh hi/lo [64][128]
    unsigned short* u7 = (unsigned short*)(ws + 58880);
    cvt<64 * 64>(s5, u7 + 0,     u7 + 4096,  t0, stride);      // Aq7
    cvt<64 * 64>(s6, u7 + 8192,  u7 + 12288, t0, stride);      // Ak7
    cvt<64 * 64>(s7, u7 + 16384, u7 + 20480, t0, stride);      // Av7
    tr<25, 64>(s8, ws + 71168, t0, stride);                    // WoutT fp32 [64][25]
}

// ---------------- fused per-row network ------------------------------------
__global__ __launch_bounds__(256, 4) void fused_net(
    const float* __restrict__ x, const float* __restrict__ ws,
    const float* __restrict__ b_in,
    const float* __restrict__ Bq4, const float* __restrict__ Bk4, const float* __restrict__ Bv4,
    const float* __restrict__ b_h,
    const float* __restrict__ Bq7, const float* __restrict__ Bk7, const float* __restrict__ Bv7,
    const float* __restrict__ b_out,
    float* __restrict__ out) {
    __shared__ __align__(16) unsigned short hAhi[16][136], hAlo[16][136];
    __shared__ __align__(16) unsigned short h2hi[16][80],  h2lo[16][80];
    __shared__ __align__(16) float sQ[16][132];               // q fp32
    __shared__ __align__(16) unsigned short sKVb[16][132][2]; // (k,v) bf16 packed
    __shared__ __align__(16) float h3T[WAVES][64][RPW];       // attn7 out transposed
    __shared__ __align__(16) float sXT[WAVES][12][RPW];
    __shared__ __align__(16) float sY[WAVES][RPW][26];

    const int tid = threadIdx.x;
    const int w = tid >> 6;
    const int l = tid & 63;
    const int row0 = blockIdx.x * RPB + w * RPW;
    const int m16 = l & 15, quad = l >> 4;
    const int g = l & 15, r = l >> 4;      // attention mapping: 16 lanes per row
    const int R = w * RPW + r;             // block-row this lane reduces/evaluates

    const float* WinT  = ws + 0;      // [12][128] fp32
    const float* WoutT = ws + 71168;  // [64][25]  fp32

    // P0: stage x transposed (wave-private)
    if (l < 12 * RPW) {
        float v = x[row0 * 12 + l];
        int rr = l / 12, in = l - rr * 12;
        sXT[w][in][rr] = v;
    }

    // P1: h = silu(x @ Win^T + b_in); lane owns cols 2l,2l+1 -> hA bf16 hi/lo
    {
        float2 bb = *(const float2*)&b_in[2 * l];
        float a0[RPW], a1[RPW];
        #pragma unroll
        for (int rr = 0; rr < RPW; rr++) { a0[rr] = bb.x; a1[rr] = bb.y; }
        #pragma unroll
        for (int in = 0; in < 12; in++) {
            float2 wv = *(const float2*)&WinT[in * 128 + 2 * l];
            float4 xr = *(const float4*)&sXT[w][in][0];
            a0[0] = fmaf(xr.x, wv.x, a0[0]); a1[0] = fmaf(xr.x, wv.y, a1[0]);
            a0[1] = fmaf(xr.y, wv.x, a0[1]); a1[1] = fmaf(xr.y, wv.y, a1[1]);
            a0[2] = fmaf(xr.z, wv.x, a0[2]); a1[2] = fmaf(xr.z, wv.y, a1[2]);
            a0[3] = fmaf(xr.w, wv.x, a0[3]); a1[3] = fmaf(xr.w, wv.y, a1[3]);
        }
        #pragma unroll
        for (int rr = 0; rr < RPW; rr++) {
            float h0 = silu_(a0[rr]), h1 = silu_(a1[rr]);
            unsigned short h0h = bfhi(h0), h1h = bfhi(h1);
            float r0 = h0 - bf2f(h0h), r1 = h1 - bf2f(h1h);
            *(unsigned*)&hAhi[w * 4 + rr][2 * l] = (unsigned)h0h | ((unsigned)h1h << 16);
            *(unsigned*)&hAlo[w * 4 + rr][2 * l] = (unsigned)bfhi(r0) | ((unsigned)bfhi(r1) << 16);
        }
    }
    __syncthreads();

    // P2: qkv4 via MFMA bf16x3. M=16, K=128, N=384. wave w: n-tiles w*6..w*6+5.
    // Rolling register prefetch: load tile t+1's 8 fragments while computing tile t.
    {
        short8 Ah[4], Al[4];
        #pragma unroll
        for (int kt = 0; kt < 4; kt++) {
            Ah[kt] = *(const short8*)&hAhi[m16][kt * 32 + quad * 8];
            Al[kt] = *(const short8*)&hAlo[m16][kt * 32 + quad * 8];
        }
        const unsigned short* u4 = (const unsigned short*)(ws + 1536);
        short8 bh[2][4], bl[2][4];
        // preload tile 0
        {
            const int nt = w * 6;
            const int mat = nt >> 3;
            const int n = (nt & 7) * 16 + m16;
            const unsigned short* Bh = u4 + mat * 32768 + n * 128;
            const unsigned short* Bl = Bh + 16384;
            #pragma unroll
            for (int kt = 0; kt < 4; kt++) {
                bh[0][kt] = *(const short8*)&Bh[kt * 32 + quad * 8];
                bl[0][kt] = *(const short8*)&Bl[kt * 32 + quad * 8];
            }
        }
        #pragma unroll
        for (int t = 0; t < 6; t++) {
            const int cur = t & 1;
            if (t < 5) {
                const int nt = w * 6 + t + 1;
                const int mat = nt >> 3;
                const int n = (nt & 7) * 16 + m16;
                const unsigned short* Bh = u4 + mat * 32768 + n * 128;
                const unsigned short* Bl = Bh + 16384;
                #pragma unroll
                for (int kt = 0; kt < 4; kt++) {
                    bh[cur ^ 1][kt] = *(const short8*)&Bh[kt * 32 + quad * 8];
                    bl[cur ^ 1][kt] = *(const short8*)&Bl[kt * 32 + quad * 8];
                }
            }
            const int nt = w * 6 + t;
            const int mat = nt >> 3;           // 0=q,1=k,2=v (wave-uniform)
            const int n = (nt & 7) * 16 + m16;
            const float* bp = (mat == 0) ? Bq4 : (mat == 1) ? Bk4 : Bv4;
            float b = bp[n];
            f32x4 acc = {b, b, b, b};
            #pragma unroll
            for (int kt = 0; kt < 4; kt++) {
                acc = __builtin_amdgcn_mfma_f32_16x16x32_bf16(Ah[kt], bh[cur][kt], acc, 0, 0, 0);
                acc = __builtin_amdgcn_mfma_f32_16x16x32_bf16(Ah[kt], bl[cur][kt], acc, 0, 0, 0);
                acc = __builtin_amdgcn_mfma_f32_16x16x32_bf16(Al[kt], bh[cur][kt], acc, 0, 0, 0);
            }
            #pragma unroll
            for (int reg = 0; reg < 4; reg++) {
                int row = quad * 4 + reg;
                float val = silu_(acc[reg]);
                if (mat == 0)      sQ[row][n] = val;
                else if (mat == 1) sKVb[row][n][0] = bfrn(val);
                else               sKVb[row][n][1] = bfrn(val);
            }
        }
    }
    __syncthreads();

    // P3: attention over 128 via Taylor moments. 16 lanes per row; lane: j,i in g*8..g*8+7
    {
        float dmom[NM];       // delta_1..14
        float nmom[NM + 1];   // nu_0..14
        #pragma unroll
        for (int m = 0; m < NM; m++) dmom[m] = 0.f;
        #pragma unroll
        for (int m = 0; m <= NM; m++) nmom[m] = 0.f;
        uint4 u0 = *(const uint4*)&sKVb[R][g * 8][0];
        uint4 u1 = *(const uint4*)&sKVb[R][g * 8 + 4][0];
        unsigned us[8] = {u0.x, u0.y, u0.z, u0.w, u1.x, u1.y, u1.z, u1.w};
        #pragma unroll
        for (int jj = 0; jj < 8; jj++) {
            unsigned u = us[jj];
            float kf = __uint_as_float(u << 16);
            float vf = __uint_as_float(u & 0xffff0000u);
            nmom[0] += vf;
            float p = kf;
            dmom[0] += p; nmom[1] = fmaf(vf, p, nmom[1]);
            #pragma unroll
            for (int m = 1; m < NM; m++) {
                p *= kf;
                dmom[m] += p;
                nmom[m + 1] = fmaf(vf, p, nmom[m + 1]);
            }
        }
        #pragma unroll
        for (int m = 0; m < NM; m++) {
            float v = dmom[m];
            v += __shfl_xor(v, 1); v += __shfl_xor(v, 2);
            v += __shfl_xor(v, 4); v += __shfl_xor(v, 8);
            dmom[m] = v;
        }
        #pragma unroll
        for (int m = 0; m <= NM; m++) {
            float v = nmom[m];
            v += __shfl_xor(v, 1); v += __shfl_xor(v, 2);
            v += __shfl_xor(v, 4); v += __shfl_xor(v, 8);
            nmom[m] = v;
        }
        float cd[NM + 1], cn[NM + 1];
        cd[0] = 128.f; cn[0] = nmom[0];
        #pragma unroll
        for (int m = 1; m <= NM; m++) {
            cd[m] = dmom[m - 1] * c_invfact[m];
            cn[m] = nmom[m] * c_invfact[m];
        }
        float4 qa = *(const float4*)&sQ[R][g * 8];
        float4 qb = *(const float4*)&sQ[R][g * 8 + 4];
        float qs[8] = {qa.x, qa.y, qa.z, qa.w, qb.x, qb.y, qb.z, qb.w};
        unsigned hiw[4], low[4];
        #pragma unroll
        for (int i = 0; i < 8; i++) {
            float t = qs[i];
            float d = cd[NM], nn = cn[NM];
            #pragma unroll
            for (int m = NM - 1; m >= 0; m--) {
                d = fmaf(d, t, cd[m]);
                nn = fmaf(nn, t, cn[m]);
            }
            float o = silu_(nn * rcpf_(d));
            unsigned short oh = bfhi(o);
            unsigned short olo = bfhi(o - bf2f(oh));
            if (i & 1) { hiw[i >> 1] |= ((unsigned)oh) << 16; low[i >> 1] |= ((unsigned)olo) << 16; }
            else       { hiw[i >> 1] = oh; low[i >> 1] = olo; }
        }
        *(uint4*)&hAhi[R][g * 8] = make_uint4(hiw[0], hiw[1], hiw[2], hiw[3]);
        *(uint4*)&hAlo[R][g * 8] = make_uint4(low[0], low[1], low[2], low[3]);
    }
    __syncthreads();

    // P4: h2 = silu(attn4 @ Wh^T + b_h) via MFMA bf16x3. K=128, N=64; wave w: tile w.
    // B fragments prefetched up-front (independent loads), then A from LDS.
    {
        const unsigned short* whh = (const unsigned short*)(ws + 50688);
        const unsigned short* whl = whh + 8192;
        const int n = w * 16 + m16;
        short8 bh[4], bl[4];
        #pragma unroll
        for (int kt = 0; kt < 4; kt++) {
            bh[kt] = *(const short8*)&whh[n * 128 + kt * 32 + quad * 8];
            bl[kt] = *(const short8*)&whl[n * 128 + kt * 32 + quad * 8];
        }
        short8 Ah[4], Al[4];
        #pragma unroll
        for (int kt = 0; kt < 4; kt++) {
            Ah[kt] = *(const short8*)&hAhi[m16][kt * 32 + quad * 8];
            Al[kt] = *(const short8*)&hAlo[m16][kt * 32 + quad * 8];
        }
        float b = b_h[n];
        f32x4 acc = {b, b, b, b};
        #pragma unroll
        for (int kt = 0; kt < 4; kt++) {
            acc = __builtin_amdgcn_mfma_f32_16x16x32_bf16(Ah[kt], bh[kt], acc, 0, 0, 0);
            acc = __builtin_amdgcn_mfma_f32_16x16x32_bf16(Ah[kt], bl[kt], acc, 0, 0, 0);
            acc = __builtin_amdgcn_mfma_f32_16x16x32_bf16(Al[kt], bh[kt], acc, 0, 0, 0);
        }
        #pragma unroll
        for (int reg = 0; reg < 4; reg++) {
            int row = quad * 4 + reg;
            float hv = silu_(acc[reg]);
            unsigned short hh = bfhi(hv);
            h2hi[row][n] = hh;
            h2lo[row][n] = bfhi(hv - bf2f(hh));
        }
    }
    __syncthreads();

    // P5: qkv7 via MFMA bf16x3. M=16, K=64, N=192. wave w: nt = w*3..w*3+2.
    // Rolling register prefetch across the 3 tiles.
    {
        short8 Ah[2], Al[2];
        #pragma unroll
        for (int kt = 0; kt < 2; kt++) {
            Ah[kt] = *(const short8*)&h2hi[m16][kt * 32 + quad * 8];
            Al[kt] = *(const short8*)&h2lo[m16][kt * 32 + quad * 8];
        }
        const unsigned short* u7 = (const unsigned short*)(ws + 58880);
        short8 bh[2][2], bl[2][2];
        {
            const int nt = w * 3;
            const int mat = nt >> 2;
            const int n = (nt & 3) * 16 + m16;
            const unsigned short* Bh = u7 + mat * 8192 + n * 64;
            const unsigned short* Bl = Bh + 4096;
            #pragma unroll
            for (int kt = 0; kt < 2; kt++) {
                bh[0][kt] = *(const short8*)&Bh[kt * 32 + quad * 8];
                bl[0][kt] = *(const short8*)&Bl[kt * 32 + quad * 8];
            }
        }
        #pragma unroll
        for (int t = 0; t < 3; t++) {
            const int cur = t & 1;
            if (t < 2) {
                const int nt = w * 3 + t + 1;
                const int mat = nt >> 2;
                const int n = (nt & 3) * 16 + m16;
                const unsigned short* Bh = u7 + mat * 8192 + n * 64;
                const unsigned short* Bl = Bh + 4096;
                #pragma unroll
                for (int kt = 0; kt < 2; kt++) {
                    bh[cur ^ 1][kt] = *(const short8*)&Bh[kt * 32 + quad * 8];
                    bl[cur ^ 1][kt] = *(const short8*)&Bl[kt * 32 + quad * 8];
                }
            }
            const int nt = w * 3 + t;
            const int mat = nt >> 2;           // 0=q,1=k,2=v
            const int n = (nt & 3) * 16 + m16;
            const float* bp = (mat == 0) ? Bq7 : (mat == 1) ? Bk7 : Bv7;
            float b = bp[n];
            f32x4 acc = {b, b, b, b};
            #pragma unroll
            for (int kt = 0; kt < 2; kt++) {
                acc = __builtin_amdgcn_mfma_f32_16x16x32_bf16(Ah[kt], bh[cur][kt], acc, 0, 0, 0);
                acc = __builtin_amdgcn_mfma_f32_16x16x32_bf16(Ah[kt], bl[cur][kt], acc, 0, 0, 0);
                acc = __builtin_amdgcn_mfma_f32_16x16x32_bf16(Al[kt], bh[cur][kt], acc, 0, 0, 0);
            }
            #pragma unroll
            for (int reg = 0; reg < 4; reg++) {
                int row = quad * 4 + reg;
                float val = silu_(acc[reg]);
                if (mat == 0)      sQ[row][n] = val;
                else if (mat == 1) sKVb[row][n][0] = bfrn(val);
                else               sKVb[row][n][1] = bfrn(val);
            }
        }
    }
    __syncthreads();

    // P6: attention over 64 via Taylor moments; lane: j,i in g*4..g*4+3
    {
        float dmom[NM];
        float nmom[NM + 1];
        #pragma unroll
        for (int m = 0; m < NM; m++) dmom[m] = 0.f;
        #pragma unroll
        for (int m = 0; m <= NM; m++) nmom[m] = 0.f;
        uint4 u0 = *(const uint4*)&sKVb[R][g * 4][0];
        unsigned us[4] = {u0.x, u0.y, u0.z, u0.w};
        #pragma unroll
        for (int jj = 0; jj < 4; jj++) {
            unsigned u = us[jj];
            float kf = __uint_as_float(u << 16);
            float vf = __uint_as_float(u & 0xffff0000u);
            nmom[0] += vf;
            float p = kf;
            dmom[0] += p; nmom[1] = fmaf(vf, p, nmom[1]);
            #pragma unroll
            for (int m = 1; m < NM; m++) {
                p *= kf;
                dmom[m] += p;
                nmom[m + 1] = fmaf(vf, p, nmom[m + 1]);
            }
        }
        #pragma unroll
        for (int m = 0; m < NM; m++) {
            float v = dmom[m];
            v += __shfl_xor(v, 1); v += __shfl_xor(v, 2);
            v += __shfl_xor(v, 4); v += __shfl_xor(v, 8);
            dmom[m] = v;
        }
        #pragma unroll
        for (int m = 0; m <= NM; m++) {
            float v = nmom[m];
            v += __shfl_xor(v, 1); v += __shfl_xor(v, 2);
            v += __shfl_xor(v, 4); v += __shfl_xor(v, 8);
            nmom[m] = v;
        }
        float cd[NM + 1], cn[NM + 1];
        cd[0] = 64.f; cn[0] = nmom[0];
        #pragma unroll
        for (int m = 1; m <= NM; m++) {
            cd[m] = dmom[m - 1] * c_invfact[m];
            cn[m] = nmom[m] * c_invfact[m];
        }
        float4 qa = *(const float4*)&sQ[R][g * 4];
        float qs[4] = {qa.x, qa.y, qa.z, qa.w};
        #pragma unroll
        for (int i = 0; i < 4; i++) {
            float t = qs[i];
            float d = cd[NM], nn = cn[NM];
            #pragma unroll
            for (int m = NM - 1; m >= 0; m--) {
                d = fmaf(d, t, cd[m]);
                nn = fmaf(nn, t, cn[m]);
            }
            h3T[w][g * 4 + i][r] = silu_(nn * rcpf_(d));
        }
    }
    // h3T slice is wave-private from here on — no block sync needed.

    // P7: y = silu(attn7 @ Wout^T + b_out), 64 -> 25, split across lane halves
    {
        const int o = l & 31;
        const int half = l >> 5;
        const int oc = (o < 25) ? o : 0;
        float y[RPW];
        float bb = (half == 0) ? b_out[oc] : 0.f;
        #pragma unroll
        for (int rr = 0; rr < RPW; rr++) y[rr] = bb;
        const int in0 = half * 32;
        #pragma unroll 8
        for (int i = 0; i < 32; i++) {
            int in = in0 + i;
            float wv = WoutT[in * 25 + oc];
            float4 xr = *(const float4*)&h3T[w][in][0];
            y[0] = fmaf(xr.x, wv, y[0]);
            y[1] = fmaf(xr.y, wv, y[1]);
            y[2] = fmaf(xr.z, wv, y[2]);
            y[3] = fmaf(xr.w, wv, y[3]);
        }
        #pragma unroll
        for (int rr = 0; rr < RPW; rr++) {
            float full = y[rr] + __shfl_xor(y[rr], 32, 64);
            if (l < 25) sY[w][rr][l] = silu_(full);
        }
    }

    // P8: quadratic epilogue; lanes l < RPW, one row each
    if (l < RPW) {
        const int rr = l;
        float y[25];
        #pragma unroll
        for (int c = 0; c < 25; c++) y[c] = sY[w][rr][c];
        float M11 = 0.f, M12 = 0.f, M21 = 0.f, M22 = 0.f, Mpp = 0.f;
        #pragma unroll
        for (int c = 0; c < 5; c++) {
            M11 = fmaf(y[c], y[c], M11);
            M12 = fmaf(y[5 + c], y[5 + c], M12);
            M21 = fmaf(y[10 + c], y[10 + c], M21);
            M22 = fmaf(y[15 + c], y[15 + c], M22);
            Mpp = fmaf(y[20 + c], y[20 + c], Mpp);
        }
        float quad = M11 * (y[0] * y[0] + y[1] * y[1])
                   + (M12 + M21) * (y[0] * y[2] + y[1] * y[3])
                   + M22 * (y[2] * y[2] + y[3] * y[3]);
        out[row0 + rr] = quad + Mpp;
    }
}

extern "C" void kernel_launch(void* const* d_in, const int* in_sizes, int n_in,
                              void* d_out, int out_size, void* d_ws, size_t ws_size,
                              hipStream_t stream) {
    const float* x    = (const float*)d_in[0];
    const float* W_in = (const float*)d_in[2];
    const float* b_in = (const float*)d_in[3];
    const float* Aq4  = (const float*)d_in[4];
    const float* Bq4  = (const float*)d_in[5];
    const float* Ak4  = (const float*)d_in[6];
    const float* Bk4  = (const float*)d_in[7];
    const float* Av4  = (const float*)d_in[8];
    const float* Bv4  = (const float*)d_in[9];
    const float* W_h  = (const float*)d_in[10];
    const float* b_h  = (const float*)d_in[11];
    const float* Aq7  = (const float*)d_in[12];
    const float* Bq7  = (const float*)d_in[13];
    const float* Ak7  = (const float*)d_in[14];
    const float* Bk7  = (const float*)d_in[15];
    const float* Av7  = (const float*)d_in[16];
    const float* Bv7  = (const float*)d_in[17];
    const float* Wout = (const float*)d_in[18];
    const float* bout = (const float*)d_in[19];
    float* ws = (float*)d_ws;

    tweights<<<256, 256, 0, stream>>>(W_in, Aq4, Ak4, Av4, W_h, Aq7, Ak7, Av7, Wout, ws);

    const int B = in_sizes[0] / 12;        // 16384
    const int grid = B / RPB;              // 1024
    fused_net<<<grid, 256, 0, stream>>>(x, ws, b_in, Bq4, Bk4, Bv4,
                                        b_h, Bq7, Bk7, Bv7, bout, (float*)d_out);
}

// Round 7
// 134.653 us; speedup vs baseline: 1.6644x; 1.0354x over previous
//
#include <hip/hip_runtime.h>

#define RPW 4            // rows per wave
#define WAVES 4
#define RPB (RPW * WAVES)   // 16 rows per block
#define NM 14               // Taylor degree (terms 0..14)

using short8 = __attribute__((ext_vector_type(8))) short;
using f32x4  = __attribute__((ext_vector_type(4))) float;

#define LOG2E 1.4426950408889634f

static __device__ __forceinline__ float ex2(float x) { return __builtin_amdgcn_exp2f(x); }
static __device__ __forceinline__ float rcpf_(float x) { return __builtin_amdgcn_rcpf(x); }
static __device__ __forceinline__ float silu_(float x) {
    return x * rcpf_(1.0f + ex2(-x * LOG2E));
}
static __device__ __forceinline__ unsigned short bfhi(float x) {          // truncate
    return (unsigned short)(__float_as_uint(x) >> 16);
}
static __device__ __forceinline__ unsigned short bfrn(float x) {          // round-nearest
    unsigned u = __float_as_uint(x);
    return (unsigned short)((u + 0x7fffu + ((u >> 16) & 1u)) >> 16);
}
static __device__ __forceinline__ float bf2f(unsigned short h) {
    return __uint_as_float(((unsigned)h) << 16);
}

// ---- DPP 16-lane rotation-sum: VALU pipe, zero LDS traffic ------------------
template <int CTRL>
static __device__ __forceinline__ float dpp_rot(float v) {
    return __uint_as_float(
        __builtin_amdgcn_update_dpp(0u, __float_as_uint(v), CTRL, 0xF, 0xF, true));
}
static __device__ __forceinline__ float rsum16(float v) {
    v += dpp_rot<0x128>(v);   // row_ror:8
    v += dpp_rot<0x124>(v);   // row_ror:4
    v += dpp_rot<0x122>(v);   // row_ror:2
    v += dpp_rot<0x121>(v);   // row_ror:1
    return v;
}

__constant__ float c_invfact[15] = {
    1.f, 1.f, 0.5f, 1.f/6, 1.f/24, 1.f/120, 1.f/720, 1.f/5040, 1.f/40320,
    1.f/362880, 1.f/3628800, 1.f/39916800, 1.f/479001600,
    1.f/6227020800.f, 1.f/87178291200.f};

// ---------------- weight prep in d_ws ---------------------------------------
template <int O, int I>
__device__ __forceinline__ void tr(const float* __restrict__ s, float* __restrict__ d,
                                   int t0, int stride) {
    for (int idx = t0; idx < O * I; idx += stride) {
        int o = idx / I, in = idx - o * I;
        d[in * O + o] = s[idx];
    }
}
template <int N>
__device__ __forceinline__ void cvt(const float* __restrict__ s,
                                    unsigned short* __restrict__ hi,
                                    unsigned short* __restrict__ lo,
                                    int t0, int stride) {
    for (int i = t0; i < N; i += stride) {
        float a = s[i];
        unsigned short h = bfhi(a);
        float r = a - bf2f(h);
        hi[i] = h;
        lo[i] = bfhi(r);
    }
}

__global__ void tweights(const float* __restrict__ s0, const float* __restrict__ s1,
                         const float* __restrict__ s2, const float* __restrict__ s3,
                         const float* __restrict__ s4, const float* __restrict__ s5,
                         const float* __restrict__ s6, const float* __restrict__ s7,
                         const float* __restrict__ s8, float* __restrict__ ws) {
    const int stride = gridDim.x * blockDim.x;
    const int t0 = blockIdx.x * blockDim.x + threadIdx.x;
    tr<128, 12>(s0, ws + 0, t0, stride);                       // WinT fp32 [12][128]
    unsigned short* u4 = (unsigned short*)(ws + 1536);
    cvt<128 * 128>(s1, u4 + 0,     u4 + 16384, t0, stride);    // Aq4 hi/lo [o][in]
    cvt<128 * 128>(s2, u4 + 32768, u4 + 49152, t0, stride);    // Ak4
    cvt<128 * 128>(s3, u4 + 65536, u4 + 81920, t0, stride);    // Av4
    unsigned short* wh = (unsigned short*)(ws + 50688);
    cvt<64 * 128>(s4, wh + 0, wh + 8192, t0, stride);          // Wh hi/lo [64][128]
    unsigned short* u7 = (unsigned short*)(ws + 58880);
    cvt<64 * 64>(s5, u7 + 0,     u7 + 4096,  t0, stride);      // Aq7
    cvt<64 * 64>(s6, u7 + 8192,  u7 + 12288, t0, stride);      // Ak7
    cvt<64 * 64>(s7, u7 + 16384, u7 + 20480, t0, stride);      // Av7
    tr<25, 64>(s8, ws + 71168, t0, stride);                    // WoutT fp32 [64][25]
}

// ---------------- fused per-row network ------------------------------------
__global__ __launch_bounds__(256, 4) void fused_net(
    const float* __restrict__ x, const float* __restrict__ ws,
    const float* __restrict__ b_in,
    const float* __restrict__ Bq4, const float* __restrict__ Bk4, const float* __restrict__ Bv4,
    const float* __restrict__ b_h,
    const float* __restrict__ Bq7, const float* __restrict__ Bk7, const float* __restrict__ Bv7,
    const float* __restrict__ b_out,
    float* __restrict__ out) {
    __shared__ __align__(16) unsigned short hAhi[16][136], hAlo[16][136];
    __shared__ __align__(16) unsigned short h2hi[16][80],  h2lo[16][80];
    __shared__ __align__(16) float sQ[16][132];               // q fp32
    __shared__ __align__(16) unsigned short sKVb[16][132][2]; // (k,v) bf16 packed
    __shared__ __align__(16) float h3T[WAVES][64][RPW];       // attn7 out transposed
    __shared__ __align__(16) float sXT[WAVES][12][RPW];
    __shared__ __align__(16) float sY[WAVES][RPW][26];

    const int tid = threadIdx.x;
    const int w = tid >> 6;
    const int l = tid & 63;
    const int row0 = blockIdx.x * RPB + w * RPW;
    const int m16 = l & 15, quad = l >> 4;
    const int g = l & 15, r = l >> 4;      // attention mapping: 16 lanes per row
    const int R = w * RPW + r;             // block-row this lane reduces/evaluates

    const float* WinT  = ws + 0;      // [12][128] fp32
    const float* WoutT = ws + 71168;  // [64][25]  fp32

    // P0: stage x transposed (wave-private)
    if (l < 12 * RPW) {
        float v = x[row0 * 12 + l];
        int rr = l / 12, in = l - rr * 12;
        sXT[w][in][rr] = v;
    }

    // P1: h = silu(x @ Win^T + b_in); lane owns cols 2l,2l+1 -> hA bf16 hi/lo
    {
        float2 bb = *(const float2*)&b_in[2 * l];
        float a0[RPW], a1[RPW];
        #pragma unroll
        for (int rr = 0; rr < RPW; rr++) { a0[rr] = bb.x; a1[rr] = bb.y; }
        #pragma unroll
        for (int in = 0; in < 12; in++) {
            float2 wv = *(const float2*)&WinT[in * 128 + 2 * l];
            float4 xr = *(const float4*)&sXT[w][in][0];
            a0[0] = fmaf(xr.x, wv.x, a0[0]); a1[0] = fmaf(xr.x, wv.y, a1[0]);
            a0[1] = fmaf(xr.y, wv.x, a0[1]); a1[1] = fmaf(xr.y, wv.y, a1[1]);
            a0[2] = fmaf(xr.z, wv.x, a0[2]); a1[2] = fmaf(xr.z, wv.y, a1[2]);
            a0[3] = fmaf(xr.w, wv.x, a0[3]); a1[3] = fmaf(xr.w, wv.y, a1[3]);
        }
        #pragma unroll
        for (int rr = 0; rr < RPW; rr++) {
            float h0 = silu_(a0[rr]), h1 = silu_(a1[rr]);
            unsigned short h0h = bfhi(h0), h1h = bfhi(h1);
            float r0 = h0 - bf2f(h0h), r1 = h1 - bf2f(h1h);
            *(unsigned*)&hAhi[w * 4 + rr][2 * l] = (unsigned)h0h | ((unsigned)h1h << 16);
            *(unsigned*)&hAlo[w * 4 + rr][2 * l] = (unsigned)bfhi(r0) | ((unsigned)bfhi(r1) << 16);
        }
    }
    __syncthreads();

    // P2: qkv4 via MFMA bf16x3. M=16, K=128, N=384. wave w: n-tiles w*6..w*6+5
    {
        short8 Ah[4], Al[4];
        #pragma unroll
        for (int kt = 0; kt < 4; kt++) {
            Ah[kt] = *(const short8*)&hAhi[m16][kt * 32 + quad * 8];
            Al[kt] = *(const short8*)&hAlo[m16][kt * 32 + quad * 8];
        }
        const unsigned short* u4 = (const unsigned short*)(ws + 1536);
        #pragma unroll
        for (int t = 0; t < 6; t++) {
            const int nt = w * 6 + t;
            const int mat = nt >> 3;           // 0=q,1=k,2=v (wave-uniform)
            const int n = (nt & 7) * 16 + m16;
            const float* bp = (mat == 0) ? Bq4 : (mat == 1) ? Bk4 : Bv4;
            float b = bp[n];
            f32x4 acc = {b, b, b, b};
            const unsigned short* Bh = u4 + mat * 32768 + n * 128;
            const unsigned short* Bl = Bh + 16384;
            #pragma unroll
            for (int kt = 0; kt < 4; kt++) {
                short8 bh = *(const short8*)&Bh[kt * 32 + quad * 8];
                short8 bl = *(const short8*)&Bl[kt * 32 + quad * 8];
                acc = __builtin_amdgcn_mfma_f32_16x16x32_bf16(Ah[kt], bh, acc, 0, 0, 0);
                acc = __builtin_amdgcn_mfma_f32_16x16x32_bf16(Ah[kt], bl, acc, 0, 0, 0);
                acc = __builtin_amdgcn_mfma_f32_16x16x32_bf16(Al[kt], bh, acc, 0, 0, 0);
            }
            #pragma unroll
            for (int reg = 0; reg < 4; reg++) {
                int row = quad * 4 + reg;
                float val = silu_(acc[reg]);
                if (mat == 0)      sQ[row][n] = val;
                else if (mat == 1) sKVb[row][n][0] = bfrn(val);
                else               sKVb[row][n][1] = bfrn(val);
            }
        }
    }
    __syncthreads();

    // P3: attention over 128 via Taylor moments. 16 lanes per row; lane: j,i in g*8..g*8+7
    {
        float dmom[NM];       // delta_1..14
        float nmom[NM + 1];   // nu_0..14
        #pragma unroll
        for (int m = 0; m < NM; m++) dmom[m] = 0.f;
        #pragma unroll
        for (int m = 0; m <= NM; m++) nmom[m] = 0.f;
        uint4 u0 = *(const uint4*)&sKVb[R][g * 8][0];
        uint4 u1 = *(const uint4*)&sKVb[R][g * 8 + 4][0];
        unsigned us[8] = {u0.x, u0.y, u0.z, u0.w, u1.x, u1.y, u1.z, u1.w};
        #pragma unroll
        for (int jj = 0; jj < 8; jj++) {
            unsigned u = us[jj];
            float kf = __uint_as_float(u << 16);
            float vf = __uint_as_float(u & 0xffff0000u);
            nmom[0] += vf;
            float p = kf;
            dmom[0] += p; nmom[1] = fmaf(vf, p, nmom[1]);
            #pragma unroll
            for (int m = 1; m < NM; m++) {
                p *= kf;
                dmom[m] += p;
                nmom[m + 1] = fmaf(vf, p, nmom[m + 1]);
            }
        }
        #pragma unroll
        for (int m = 0; m < NM; m++) dmom[m] = rsum16(dmom[m]);
        #pragma unroll
        for (int m = 0; m <= NM; m++) nmom[m] = rsum16(nmom[m]);
        float cd[NM + 1], cn[NM + 1];
        cd[0] = 128.f; cn[0] = nmom[0];
        #pragma unroll
        for (int m = 1; m <= NM; m++) {
            cd[m] = dmom[m - 1] * c_invfact[m];
            cn[m] = nmom[m] * c_invfact[m];
        }
        float4 qa = *(const float4*)&sQ[R][g * 8];
        float4 qb = *(const float4*)&sQ[R][g * 8 + 4];
        float qs[8] = {qa.x, qa.y, qa.z, qa.w, qb.x, qb.y, qb.z, qb.w};
        unsigned hiw[4], low[4];
        #pragma unroll
        for (int i = 0; i < 8; i++) {
            float t = qs[i];
            float d = cd[NM], nn = cn[NM];
            #pragma unroll
            for (int m = NM - 1; m >= 0; m--) {
                d = fmaf(d, t, cd[m]);
                nn = fmaf(nn, t, cn[m]);
            }
            float o = silu_(nn * rcpf_(d));
            unsigned short oh = bfhi(o);
            unsigned short olo = bfhi(o - bf2f(oh));
            if (i & 1) { hiw[i >> 1] |= ((unsigned)oh) << 16; low[i >> 1] |= ((unsigned)olo) << 16; }
            else       { hiw[i >> 1] = oh; low[i >> 1] = olo; }
        }
        *(uint4*)&hAhi[R][g * 8] = make_uint4(hiw[0], hiw[1], hiw[2], hiw[3]);
        *(uint4*)&hAlo[R][g * 8] = make_uint4(low[0], low[1], low[2], low[3]);
    }
    __syncthreads();

    // P4: h2 = silu(attn4 @ Wh^T + b_h) via MFMA bf16x3. K=128, N=64; wave w: tile w
    {
        short8 Ah[4], Al[4];
        #pragma unroll
        for (int kt = 0; kt < 4; kt++) {
            Ah[kt] = *(const short8*)&hAhi[m16][kt * 32 + quad * 8];
            Al[kt] = *(const short8*)&hAlo[m16][kt * 32 + quad * 8];
        }
        const unsigned short* whh = (const unsigned short*)(ws + 50688);
        const unsigned short* whl = whh + 8192;
        const int n = w * 16 + m16;
        float b = b_h[n];
        f32x4 acc = {b, b, b, b};
        #pragma unroll
        for (int kt = 0; kt < 4; kt++) {
            short8 bh = *(const short8*)&whh[n * 128 + kt * 32 + quad * 8];
            short8 bl = *(const short8*)&whl[n * 128 + kt * 32 + quad * 8];
            acc = __builtin_amdgcn_mfma_f32_16x16x32_bf16(Ah[kt], bh, acc, 0, 0, 0);
            acc = __builtin_amdgcn_mfma_f32_16x16x32_bf16(Ah[kt], bl, acc, 0, 0, 0);
            acc = __builtin_amdgcn_mfma_f32_16x16x32_bf16(Al[kt], bh, acc, 0, 0, 0);
        }
        #pragma unroll
        for (int reg = 0; reg < 4; reg++) {
            int row = quad * 4 + reg;
            float hv = silu_(acc[reg]);
            unsigned short hh = bfhi(hv);
            h2hi[row][n] = hh;
            h2lo[row][n] = bfhi(hv - bf2f(hh));
        }
    }
    __syncthreads();

    // P5: qkv7 via MFMA bf16x3. M=16, K=64, N=192. wave w: nt = w*3..w*3+2
    {
        short8 Ah[2], Al[2];
        #pragma unroll
        for (int kt = 0; kt < 2; kt++) {
            Ah[kt] = *(const short8*)&h2hi[m16][kt * 32 + quad * 8];
            Al[kt] = *(const short8*)&h2lo[m16][kt * 32 + quad * 8];
        }
        const unsigned short* u7 = (const unsigned short*)(ws + 58880);
        #pragma unroll
        for (int t = 0; t < 3; t++) {
            const int nt = w * 3 + t;
            const int mat = nt >> 2;           // 0=q,1=k,2=v
            const int n = (nt & 3) * 16 + m16;
            const float* bp = (mat == 0) ? Bq7 : (mat == 1) ? Bk7 : Bv7;
            float b = bp[n];
            f32x4 acc = {b, b, b, b};
            const unsigned short* Bh = u7 + mat * 8192 + n * 64;
            const unsigned short* Bl = Bh + 4096;
            #pragma unroll
            for (int kt = 0; kt < 2; kt++) {
                short8 bh = *(const short8*)&Bh[kt * 32 + quad * 8];
                short8 bl = *(const short8*)&Bl[kt * 32 + quad * 8];
                acc = __builtin_amdgcn_mfma_f32_16x16x32_bf16(Ah[kt], bh, acc, 0, 0, 0);
                acc = __builtin_amdgcn_mfma_f32_16x16x32_bf16(Ah[kt], bl, acc, 0, 0, 0);
                acc = __builtin_amdgcn_mfma_f32_16x16x32_bf16(Al[kt], bh, acc, 0, 0, 0);
            }
            #pragma unroll
            for (int reg = 0; reg < 4; reg++) {
                int row = quad * 4 + reg;
                float val = silu_(acc[reg]);
                if (mat == 0)      sQ[row][n] = val;
                else if (mat == 1) sKVb[row][n][0] = bfrn(val);
                else               sKVb[row][n][1] = bfrn(val);
            }
        }
    }
    __syncthreads();

    // P6: attention over 64 via Taylor moments; lane: j,i in g*4..g*4+3
    {
        float dmom[NM];
        float nmom[NM + 1];
        #pragma unroll
        for (int m = 0; m < NM; m++) dmom[m] = 0.f;
        #pragma unroll
        for (int m = 0; m <= NM; m++) nmom[m] = 0.f;
        uint4 u0 = *(const uint4*)&sKVb[R][g * 4][0];
        unsigned us[4] = {u0.x, u0.y, u0.z, u0.w};
        #pragma unroll
        for (int jj = 0; jj < 4; jj++) {
            unsigned u = us[jj];
            float kf = __uint_as_float(u << 16);
            float vf = __uint_as_float(u & 0xffff0000u);
            nmom[0] += vf;
            float p = kf;
            dmom[0] += p; nmom[1] = fmaf(vf, p, nmom[1]);
            #pragma unroll
            for (int m = 1; m < NM; m++) {
                p *= kf;
                dmom[m] += p;
                nmom[m + 1] = fmaf(vf, p, nmom[m + 1]);
            }
        }
        #pragma unroll
        for (int m = 0; m < NM; m++) dmom[m] = rsum16(dmom[m]);
        #pragma unroll
        for (int m = 0; m <= NM; m++) nmom[m] = rsum16(nmom[m]);
        float cd[NM + 1], cn[NM + 1];
        cd[0] = 64.f; cn[0] = nmom[0];
        #pragma unroll
        for (int m = 1; m <= NM; m++) {
            cd[m] = dmom[m - 1] * c_invfact[m];
            cn[m] = nmom[m] * c_invfact[m];
        }
        float4 qa = *(const float4*)&sQ[R][g * 4];
        float qs[4] = {qa.x, qa.y, qa.z, qa.w};
        #pragma unroll
        for (int i = 0; i < 4; i++) {
            float t = qs[i];
            float d = cd[NM], nn = cn[NM];
            #pragma unroll
            for (int m = NM - 1; m >= 0; m--) {
                d = fmaf(d, t, cd[m]);
                nn = fmaf(nn, t, cn[m]);
            }
            h3T[w][g * 4 + i][r] = silu_(nn * rcpf_(d));
        }
    }
    // h3T slice is wave-private from here on — no block sync needed.

    // P7: y = silu(attn7 @ Wout^T + b_out), 64 -> 25, split across lane halves
    {
        const int o = l & 31;
        const int half = l >> 5;
        const int oc = (o < 25) ? o : 0;
        float y[RPW];
        float bb = (half == 0) ? b_out[oc] : 0.f;
        #pragma unroll
        for (int rr = 0; rr < RPW; rr++) y[rr] = bb;
        const int in0 = half * 32;
        #pragma unroll 4
        for (int i = 0; i < 32; i++) {
            int in = in0 + i;
            float wv = WoutT[in * 25 + oc];
            float4 xr = *(const float4*)&h3T[w][in][0];
            y[0] = fmaf(xr.x, wv, y[0]);
            y[1] = fmaf(xr.y, wv, y[1]);
            y[2] = fmaf(xr.z, wv, y[2]);
            y[3] = fmaf(xr.w, wv, y[3]);
        }
        #pragma unroll
        for (int rr = 0; rr < RPW; rr++) {
            float full = y[rr] + __shfl_xor(y[rr], 32, 64);
            if (l < 25) sY[w][rr][l] = silu_(full);
        }
    }

    // P8: quadratic epilogue; lanes l < RPW, one row each
    if (l < RPW) {
        const int rr = l;
        float y[25];
        #pragma unroll
        for (int c = 0; c < 25; c++) y[c] = sY[w][rr][c];
        float M11 = 0.f, M12 = 0.f, M21 = 0.f, M22 = 0.f, Mpp = 0.f;
        #pragma unroll
        for (int c = 0; c < 5; c++) {
            M11 = fmaf(y[c], y[c], M11);
            M12 = fmaf(y[5 + c], y[5 + c], M12);
            M21 = fmaf(y[10 + c], y[10 + c], M21);
            M22 = fmaf(y[15 + c], y[15 + c], M22);
            Mpp = fmaf(y[20 + c], y[20 + c], Mpp);
        }
        float quad = M11 * (y[0] * y[0] + y[1] * y[1])
                   + (M12 + M21) * (y[0] * y[2] + y[1] * y[3])
                   + M22 * (y[2] * y[2] + y[3] * y[3]);
        out[row0 + rr] = quad + Mpp;
    }
}

extern "C" void kernel_launch(void* const* d_in, const int* in_sizes, int n_in,
                              void* d_out, int out_size, void* d_ws, size_t ws_size,
                              hipStream_t stream) {
    const float* x    = (const float*)d_in[0];
    const float* W_in = (const float*)d_in[2];
    const float* b_in = (const float*)d_in[3];
    const float* Aq4  = (const float*)d_in[4];
    const float* Bq4  = (const float*)d_in[5];
    const float* Ak4  = (const float*)d_in[6];
    const float* Bk4  = (const float*)d_in[7];
    const float* Av4  = (const float*)d_in[8];
    const float* Bv4  = (const float*)d_in[9];
    const float* W_h  = (const float*)d_in[10];
    const float* b_h  = (const float*)d_in[11];
    const float* Aq7  = (const float*)d_in[12];
    const float* Bq7  = (const float*)d_in[13];
    const float* Ak7  = (const float*)d_in[14];
    const float* Bk7  = (const float*)d_in[15];
    const float* Av7  = (const float*)d_in[16];
    const float* Bv7  = (const float*)d_in[17];
    const float* Wout = (const float*)d_in[18];
    const float* bout = (const float*)d_in[19];
    float* ws = (float*)d_ws;

    tweights<<<256, 256, 0, stream>>>(W_in, Aq4, Ak4, Av4, W_h, Aq7, Ak7, Av7, Wout, ws);

    const int B = in_sizes[0] / 12;        // 16384
    const int grid = B / RPB;              // 1024
    fused_net<<<grid, 256, 0, stream>>>(x, ws, b_in, Bq4, Bk4, Bv4,
                                        b_h, Bq7, Bk7, Bv7, bout, (float*)d_out);
}